// Round 18
// baseline (15911.629 us; speedup 1.0000x reference)
//
#include <hip/hip_runtime.h>

#define B_   64
#define S_   512
#define EMB_ 512
#define HID_ 1024
#define NBLK_ 256

typedef float    f32x4 __attribute__((ext_vector_type(4)));
typedef unsigned u32x4 __attribute__((ext_vector_type(4)));

// Transport model (R18): cross-block WRITES go sc0 sc1 (straight to the IC =
// coherent point; L2 never holds dirty shared lines). Cross-block READS are
// plain cached, preceded per-wait by an acquire fence (L1/L2 inv) so refills
// pull the fresh IC copy and the XCD L2 serves the 16x read redundancy.
// Flag polls remain sc0 sc1 (the synchronizes-with edge).
// RULES: (R9) inline-asm loads need explicit waits (polls embed theirs).
// (R12) no runtime-indexed ext_vector arrays. (R16) XCC_ID mirror banned.
__device__ __forceinline__ void st_coh4(float* p, f32x4 v) {
    asm volatile("global_store_dwordx4 %0, %1, off sc0 sc1" :: "v"(p), "v"(v) : "memory");
}
__device__ __forceinline__ void st_coh1u(unsigned* p, unsigned v) {
    asm volatile("global_store_dword %0, %1, off sc0 sc1" :: "v"(p), "v"(v) : "memory");
}
// Poll load with embedded vmcnt wait — result valid at asm exit.
__device__ __forceinline__ unsigned ld_cohu_wait(const unsigned* p) {
    unsigned d;
    asm volatile("global_load_dword %0, %1, off sc0 sc1\n\t"
                 "s_waitcnt vmcnt(0)"
                 : "=v"(d) : "v"(p) : "memory");
    return d;
}

// ---------------------------------------------------------------------------
// Kernel A: X1[t][b][n] = emb[x[b][t]][:] @ Wi1[:,n] + b1[n]  (fp32; chaotic
// recurrence -> no reduced precision anywhere feeding it, R6)
// ---------------------------------------------------------------------------
__global__ __launch_bounds__(256) void embed_gemm(
    const int* __restrict__ x, const float* __restrict__ emb,
    const float* __restrict__ Wi1, const float* __restrict__ b1,
    float* __restrict__ X1)
{
    __shared__ int   tok[128];
    __shared__ float aT[32][132];
    __shared__ float bl[32][68];

    const int tid = threadIdx.x;
    const int m0  = blockIdx.y * 128;
    const int n0  = blockIdx.x * 64;

    if (tid < 128) {
        int m = m0 + tid;
        tok[tid] = x[(m & 63) * S_ + (m >> 6)];
    }
    __syncthreads();

    const int tx = tid & 15;
    const int ty = tid >> 4;

    float acc[8][4];
#pragma unroll
    for (int r = 0; r < 8; ++r)
#pragma unroll
        for (int c = 0; c < 4; ++c) acc[r][c] = 0.f;

    for (int kt = 0; kt < EMB_; kt += 32) {
#pragma unroll
        for (int j = 0; j < 4; ++j) {
            int idx = tid + j * 256;
            int r   = idx >> 3;
            int k4  = (idx & 7) * 4;
            float4 v = *(const float4*)(emb + (size_t)tok[r] * EMB_ + kt + k4);
            aT[k4 + 0][r] = v.x; aT[k4 + 1][r] = v.y;
            aT[k4 + 2][r] = v.z; aT[k4 + 3][r] = v.w;
        }
#pragma unroll
        for (int j = 0; j < 2; ++j) {
            int idx = tid + j * 256;
            int k   = idx >> 4;
            int c4  = (idx & 15) * 4;
            *(float4*)&bl[k][c4] =
                *(const float4*)(Wi1 + (size_t)(kt + k) * HID_ + n0 + c4);
        }
        __syncthreads();

#pragma unroll 4
        for (int k = 0; k < 32; ++k) {
            float4 a0 = *(const float4*)&aT[k][ty * 8];
            float4 a1 = *(const float4*)&aT[k][ty * 8 + 4];
            float4 bv = *(const float4*)&bl[k][tx * 4];
            float ar[8] = {a0.x, a0.y, a0.z, a0.w, a1.x, a1.y, a1.z, a1.w};
            float bc[4] = {bv.x, bv.y, bv.z, bv.w};
#pragma unroll
            for (int r = 0; r < 8; ++r)
#pragma unroll
                for (int c = 0; c < 4; ++c) acc[r][c] += ar[r] * bc[c];
        }
        __syncthreads();
    }

    float4 bias = *(const float4*)(b1 + n0 + tx * 4);
#pragma unroll
    for (int r = 0; r < 8; ++r) {
        int m = m0 + ty * 8 + r;
        float4 o;
        o.x = acc[r][0] + bias.x; o.y = acc[r][1] + bias.y;
        o.z = acc[r][2] + bias.z; o.w = acc[r][3] + bias.w;
        *(float4*)(X1 + (size_t)m * HID_ + n0 + tx * 4) = o;
    }
}

// shfl_xor of a whole f32x4 (per component)
__device__ __forceinline__ f32x4 shfl_xor4(f32x4 v, int m) {
    f32x4 r;
#pragma unroll
    for (int e = 0; e < 4; ++e) r[e] = __shfl_xor(v[e], m, 64);
    return r;
}

// ---------------------------------------------------------------------------
// Kernel B: persistent 3D-split scan (2 x 8 x 16), sparse producer waits
// (R17 skeleton), L2-cached reads + per-wait acquire fence (R18 transport).
// ---------------------------------------------------------------------------
__global__ __launch_bounds__(256, 1) void rnn_scan(
    const float* __restrict__ X1, const float* __restrict__ Wh1,
    const float* __restrict__ Wi2, const float* __restrict__ Wh2,
    const float* __restrict__ b2, float* __restrict__ hb,
    float* __restrict__ p1, float* __restrict__ p2,
    unsigned int* __restrict__ flagsA, unsigned int* __restrict__ flagsB)
{
    __shared__ float w1s[128 * 64];   // Wh1 slice [k][c], 32 KB
    __shared__ float w2s[128 * 64];   // Wi2 slice
    __shared__ float w3s[128 * 64];   // Wh2 slice

    const int tid = threadIdx.x;
    const int bk  = blockIdx.x;
    const int rg  = bk >> 7;          // 0..1  row half
    const int kg  = (bk >> 4) & 7;    // 0..7  k-group (128 k)
    const int cg  = bk & 15;          // 0..15 col-group (64 cols)
    const int jj  = bk & 127;         // phase-B role: cols [8jj, 8jj+8)
    const int k0  = kg * 128;
    const int cs0 = cg * 64;
    const int r0  = rg * 32;

    // ---- stage weight slices (once): 128 k x 64 cols x 3 ----
    for (int idx = tid; idx < 2048; idx += 256) {
        int k = idx >> 4, c4 = (idx & 15) * 4;
        *(f32x4*)&w1s[k * 64 + c4] = *(const f32x4*)(Wh1 + (size_t)(k0 + k) * HID_ + cs0 + c4);
        *(f32x4*)&w2s[k * 64 + c4] = *(const f32x4*)(Wi2 + (size_t)(k0 + k) * HID_ + cs0 + c4);
        *(f32x4*)&w3s[k * 64 + c4] = *(const f32x4*)(Wh2 + (size_t)(k0 + k) * HID_ + cs0 + c4);
    }

    const int row32 = tid >> 3;       // 0..31 (phase A & B row)
    const int c8    = tid & 7;        // 0..7  phase-A col-octet
    const int kq8   = tid & 7;        // 0..7  phase-B kg lane

    const f32x4 b2va = *(const f32x4*)(b2 + jj * 8);
    const f32x4 b2vb = *(const f32x4*)(b2 + jj * 8 + 4);

    float* h1buf[2] = { hb, hb + 65536 };
    float* h2buf[2] = { hb + 131072, hb + 196608 };

    __syncthreads();

    for (int i = 0; i <= S_; ++i) {
        // ---- W1: sparse wait on step-(i-1) phase-B producers (same rg) ----
        if (i >= 1) {
            const unsigned* fb = flagsB + (size_t)(i - 1) * 256 + rg * 128;
            if (tid < 24) {
                int idx = (tid < 16) ? (kg * 16 + tid) : (cg * 8 + (tid - 16));
                while (ld_cohu_wait(fb + idx) == 0) __builtin_amdgcn_s_sleep(1);
            }
            __syncthreads();
            // acquire: invalidate L1/L2 so plain h reads refill from IC
            __builtin_amdgcn_fence(__ATOMIC_ACQUIRE, "agent");
        }

        // ---- phase A: h row (r0+row32), k slice [k0, k0+128), plain reads ----
        const float* h1src = h1buf[(i + 1) & 1] + (r0 + row32) * HID_ + k0;
        const float* h2src = h2buf[i & 1]       + (r0 + row32) * HID_ + k0;

        f32x4 a1lo = {0,0,0,0}, a1hi = {0,0,0,0};
        f32x4 a2lo = {0,0,0,0}, a2hi = {0,0,0,0};

#pragma unroll 8
        for (int q = 0; q < 32; ++q) {
            f32x4 hv1 = *(const f32x4*)(h1src + q * 4);
            f32x4 hv2 = *(const f32x4*)(h2src + q * 4);
#pragma unroll
            for (int e = 0; e < 4; ++e) {
                const int kk = q * 4 + e;
                const float hx = hv1[e];
                const float hy = hv2[e];
                const float* w1r = &w1s[kk * 64 + c8 * 8];
                const float* w2r = &w2s[kk * 64 + c8 * 8];
                const float* w3r = &w3s[kk * 64 + c8 * 8];
                f32x4 wv1a = *(const f32x4*)(w1r);
                f32x4 wv1b = *(const f32x4*)(w1r + 4);
                f32x4 wv2a = *(const f32x4*)(w2r);
                f32x4 wv2b = *(const f32x4*)(w2r + 4);
                f32x4 wv3a = *(const f32x4*)(w3r);
                f32x4 wv3b = *(const f32x4*)(w3r + 4);
                a1lo += hx * wv1a;  a1hi += hx * wv1b;
                a2lo += hx * wv2a + hy * wv3a;
                a2hi += hx * wv2b + hy * wv3b;
            }
        }

        // ---- write partials (sc0sc1 -> IC): p[kg][r0+row32][cs0+8c8..+8] ----
        {
            float* pp1 = p1 + ((size_t)kg * 64 + r0 + row32) * HID_ + cs0 + c8 * 8;
            float* pp2 = p2 + ((size_t)kg * 64 + r0 + row32) * HID_ + cs0 + c8 * 8;
            st_coh4(pp1,     a1lo); st_coh4(pp1 + 4, a1hi);
            st_coh4(pp2,     a2lo); st_coh4(pp2 + 4, a2hi);
        }

        // ---- signal p ready ----
        asm volatile("s_waitcnt vmcnt(0)" ::: "memory");
        __syncthreads();
        if (tid == 0) st_coh1u(flagsA + (size_t)i * 256 + bk, 1u);

        // ---- W2: wait my 8 kg-producers (rg, kg', cg'=jj>>3) ----
        {
            const unsigned* fa = flagsA + (size_t)i * 256 + rg * 128;
            if (tid < 8) {
                while (ld_cohu_wait(fa + tid * 16 + (jj >> 3)) == 0)
                    __builtin_amdgcn_s_sleep(1);
            }
            __syncthreads();
            // acquire: invalidate so plain p reads refill from IC
            __builtin_amdgcn_fence(__ATOMIC_ACQUIRE, "agent");
        }

        // ---- phase B: thread (row32, kq8) reduces over kq8 lanes ----
        {
            const float* q1 = p1 + ((size_t)kq8 * 64 + r0 + row32) * HID_ + jj * 8;
            const float* q2 = p2 + ((size_t)kq8 * 64 + r0 + row32) * HID_ + jj * 8;
            f32x4 s1a = *(const f32x4*)(q1);
            f32x4 s1b = *(const f32x4*)(q1 + 4);
            f32x4 s2a = *(const f32x4*)(q2);
            f32x4 s2b = *(const f32x4*)(q2 + 4);

            f32x4 xva = {0,0,0,0}, xvb = {0,0,0,0};
            if (i < S_) {   // plain cached (X1 includes b1)
                const float* xp = X1 + ((size_t)i * B_ + r0 + row32) * HID_ + jj * 8;
                xva = *(const f32x4*)(xp);
                xvb = *(const f32x4*)(xp + 4);
            }

#pragma unroll
            for (int m = 1; m <= 4; m <<= 1) {
                s1a += shfl_xor4(s1a, m);
                s1b += shfl_xor4(s1b, m);
                s2a += shfl_xor4(s2a, m);
                s2b += shfl_xor4(s2b, m);
            }

            if (kq8 == 0) {
                const int row = r0 + row32;
                if (i < S_) {
                    f32x4 oa, ob;
#pragma unroll
                    for (int e = 0; e < 4; ++e) {
                        oa[e] = tanhf(xva[e] + s1a[e]);
                        ob[e] = tanhf(xvb[e] + s1b[e]);
                    }
                    float* hp = h1buf[i & 1] + row * HID_ + jj * 8;
                    st_coh4(hp, oa); st_coh4(hp + 4, ob);
                }
                if (i >= 1) {
                    f32x4 oa, ob;
#pragma unroll
                    for (int e = 0; e < 4; ++e) {
                        oa[e] = tanhf(s2a[e] + b2va[e]);
                        ob[e] = tanhf(s2b[e] + b2vb[e]);
                    }
                    float* hp = h2buf[(i + 1) & 1] + row * HID_ + jj * 8;
                    st_coh4(hp, oa); st_coh4(hp + 4, ob);
                }
            }
        }

        // ---- signal h ready ----
        if (i < S_) {
            asm volatile("s_waitcnt vmcnt(0)" ::: "memory");
            __syncthreads();
            if (tid == 0) st_coh1u(flagsB + (size_t)i * 256 + bk, 1u);
        }
    }
    // h2(S-1) sits in h2buf[1] (= hb + 196608)
}

// ---------------------------------------------------------------------------
// out[b] = sigmoid(h2_last[b,:] @ Wd + bd)
// ---------------------------------------------------------------------------
__global__ void dense_sigmoid(const float* __restrict__ h2,
                              const float* __restrict__ Wd,
                              const float* __restrict__ bd,
                              float* __restrict__ out)
{
    int b = blockIdx.x, lane = threadIdx.x;
    float s = 0.f;
    for (int j = lane; j < HID_; j += 64) s += h2[b * HID_ + j] * Wd[j];
#pragma unroll
    for (int off = 32; off > 0; off >>= 1) s += __shfl_down(s, off, 64);
    if (lane == 0) out[b] = 1.f / (1.f + expf(-(s + bd[0])));
}

// ---------------------------------------------------------------------------
// ws layout (bytes) — identical to R15/R17:
//   hb     @ 0          1,048,576  (4 h buffers fp32)
//   flagsA @ 1,048,576    525,312  (513 steps x 256 u32, [i][bk])
//   flagsB @ 1,573,888    524,288  (512 steps x 256 u32, [i][bk])
//   p1     @ 2,098,176  2,097,152  (8 kg x 64 rows x 1024 cols fp32)
//   p2     @ 4,195,328  2,097,152
//   X1     @ 6,292,480  134,217,728 (S*B*HID fp32)
// memset zeroes hb+flagsA+flagsB = 2,098,176 B. (p1/p2/X1 written before read.)
// ---------------------------------------------------------------------------
extern "C" void kernel_launch(void* const* d_in, const int* in_sizes, int n_in,
                              void* d_out, int out_size, void* d_ws, size_t ws_size,
                              hipStream_t stream)
{
    const int*   x   = (const int*)  d_in[0];
    const float* emb = (const float*)d_in[1];
    const float* Wi1 = (const float*)d_in[2];
    const float* Wh1 = (const float*)d_in[3];
    const float* b1  = (const float*)d_in[4];
    const float* Wi2 = (const float*)d_in[5];
    const float* Wh2 = (const float*)d_in[6];
    const float* b2  = (const float*)d_in[7];
    const float* Wd  = (const float*)d_in[8];
    const float* bd  = (const float*)d_in[9];
    float* out = (float*)d_out;

    char* w = (char*)d_ws;
    float*        hb     = (float*)w;
    unsigned int* flagsA = (unsigned int*)(w + 1048576);
    unsigned int* flagsB = (unsigned int*)(w + 1573888);
    float*        p1     = (float*)(w + 2098176);
    float*        p2     = (float*)(w + 4195328);
    float*        X1     = (float*)(w + 6292480);

    hipMemsetAsync(w, 0, 2098176, stream);

    dim3 gA(HID_ / 64, (S_ * B_) / 128);
    embed_gemm<<<gA, dim3(256), 0, stream>>>(x, emb, Wi1, b1, X1);

    const float* X1c = X1;
    void* args[] = { (void*)&X1c, (void*)&Wh1, (void*)&Wi2, (void*)&Wh2,
                     (void*)&b2, (void*)&hb, (void*)&p1, (void*)&p2,
                     (void*)&flagsA, (void*)&flagsB };
    hipLaunchCooperativeKernel((const void*)rnn_scan, dim3(NBLK_), dim3(256),
                               args, 0, stream);

    dense_sigmoid<<<64, 64, 0, stream>>>(hb + 196608, Wd, bd, out);
}

// Round 19
// 12189.927 us; speedup vs baseline: 1.3053x; 1.3053x over previous
//
#include <hip/hip_runtime.h>

#define B_   64
#define S_   512
#define EMB_ 512
#define HID_ 1024
#define NBLK_ 256

typedef float    f32x4 __attribute__((ext_vector_type(4)));
typedef unsigned u32x4 __attribute__((ext_vector_type(4)));

// Coherent (IC/HBM-path) access: sc0 sc1 bypasses L1+L2 -> no cache-wide
// fences needed for cross-XCD exchange. Proven R5/R8/R10/R11/R14/R15/R17.
// RULES: (R9) inline-asm loads get NO compiler-inserted s_waitcnt — every
// consumer needs an explicit vmcnt wait + sched_barrier(0). (R12) no
// runtime-indexed ext_vector arrays. (R16) XCC_ID L2-mirror banned.
// (R18) cached reads + acquire fences self-defeat (32 blocks/XCD wipe each
// other's L2); sc0sc1 transport it is. (R19) pack exchange data into full
// 64B units — partial-line sc0sc1 traffic is accounted/serviced as full
// sectors (R17: WRITE_SIZE 2x actual bytes).
__device__ __forceinline__ f32x4 ld_coh4(const float* p) {
    f32x4 d;
    asm volatile("global_load_dwordx4 %0, %1, off sc0 sc1" : "=v"(d) : "v"(p));
    return d;
}
__device__ __forceinline__ void st_coh4(float* p, f32x4 v) {
    asm volatile("global_store_dwordx4 %0, %1, off sc0 sc1" :: "v"(p), "v"(v) : "memory");
}
__device__ __forceinline__ void st_coh1u(unsigned* p, unsigned v) {
    asm volatile("global_store_dword %0, %1, off sc0 sc1" :: "v"(p), "v"(v) : "memory");
}
// Poll loads with embedded vmcnt wait — result valid at asm exit.
__device__ __forceinline__ unsigned ld_cohu_wait(const unsigned* p) {
    unsigned d;
    asm volatile("global_load_dword %0, %1, off sc0 sc1\n\t"
                 "s_waitcnt vmcnt(0)"
                 : "=v"(d) : "v"(p) : "memory");
    return d;
}
__device__ __forceinline__ u32x4 ld_coh4u_wait(const unsigned* p) {
    u32x4 d;
    asm volatile("global_load_dwordx4 %0, %1, off sc0 sc1\n\t"
                 "s_waitcnt vmcnt(0)"
                 : "=v"(d) : "v"(p) : "memory");
    return d;
}

// ---------------------------------------------------------------------------
// Kernel A: X1[t][b][n] = emb[x[b][t]][:] @ Wi1[:,n] + b1[n]  (fp32; chaotic
// recurrence -> no reduced precision anywhere feeding it, R6)
// ---------------------------------------------------------------------------
__global__ __launch_bounds__(256) void embed_gemm(
    const int* __restrict__ x, const float* __restrict__ emb,
    const float* __restrict__ Wi1, const float* __restrict__ b1,
    float* __restrict__ X1)
{
    __shared__ int   tok[128];
    __shared__ float aT[32][132];
    __shared__ float bl[32][68];

    const int tid = threadIdx.x;
    const int m0  = blockIdx.y * 128;
    const int n0  = blockIdx.x * 64;

    if (tid < 128) {
        int m = m0 + tid;
        tok[tid] = x[(m & 63) * S_ + (m >> 6)];
    }
    __syncthreads();

    const int tx = tid & 15;
    const int ty = tid >> 4;

    float acc[8][4];
#pragma unroll
    for (int r = 0; r < 8; ++r)
#pragma unroll
        for (int c = 0; c < 4; ++c) acc[r][c] = 0.f;

    for (int kt = 0; kt < EMB_; kt += 32) {
#pragma unroll
        for (int j = 0; j < 4; ++j) {
            int idx = tid + j * 256;
            int r   = idx >> 3;
            int k4  = (idx & 7) * 4;
            float4 v = *(const float4*)(emb + (size_t)tok[r] * EMB_ + kt + k4);
            aT[k4 + 0][r] = v.x; aT[k4 + 1][r] = v.y;
            aT[k4 + 2][r] = v.z; aT[k4 + 3][r] = v.w;
        }
#pragma unroll
        for (int j = 0; j < 2; ++j) {
            int idx = tid + j * 256;
            int k   = idx >> 4;
            int c4  = (idx & 15) * 4;
            *(float4*)&bl[k][c4] =
                *(const float4*)(Wi1 + (size_t)(kt + k) * HID_ + n0 + c4);
        }
        __syncthreads();

#pragma unroll 4
        for (int k = 0; k < 32; ++k) {
            float4 a0 = *(const float4*)&aT[k][ty * 8];
            float4 a1 = *(const float4*)&aT[k][ty * 8 + 4];
            float4 bv = *(const float4*)&bl[k][tx * 4];
            float ar[8] = {a0.x, a0.y, a0.z, a0.w, a1.x, a1.y, a1.z, a1.w};
            float bc[4] = {bv.x, bv.y, bv.z, bv.w};
#pragma unroll
            for (int r = 0; r < 8; ++r)
#pragma unroll
                for (int c = 0; c < 4; ++c) acc[r][c] += ar[r] * bc[c];
        }
        __syncthreads();
    }

    float4 bias = *(const float4*)(b1 + n0 + tx * 4);
#pragma unroll
    for (int r = 0; r < 8; ++r) {
        int m = m0 + ty * 8 + r;
        float4 o;
        o.x = acc[r][0] + bias.x; o.y = acc[r][1] + bias.y;
        o.z = acc[r][2] + bias.z; o.w = acc[r][3] + bias.w;
        *(float4*)(X1 + (size_t)m * HID_ + n0 + tx * 4) = o;
    }
}

// shfl_xor of a whole f32x4 (per component)
__device__ __forceinline__ f32x4 shfl_xor4(f32x4 v, int m) {
    f32x4 r;
#pragma unroll
    for (int e = 0; e < 4; ++e) r[e] = __shfl_xor(v[e], m, 64);
    return r;
}

// ---------------------------------------------------------------------------
// Kernel B: persistent 3D-split scan (rows x k x cols = 2 x 8 x 16), sparse
// producer waits (R17 skeleton). R19 change: p1/p2 interleaved into 64B
// units pbuf[(kg*64+row)*128 + j] = {a1lo,a1hi,a2lo,a2hi} for col-octet j —
// phase-A write = one full 64B line per thread, phase-B read = one full
// 64B line per lane. W1 flag polls vectorized to dwordx4.
// ---------------------------------------------------------------------------
__global__ __launch_bounds__(256, 1) void rnn_scan(
    const float* __restrict__ X1, const float* __restrict__ Wh1,
    const float* __restrict__ Wi2, const float* __restrict__ Wh2,
    const float* __restrict__ b2, float* __restrict__ hb,
    float* __restrict__ pbuf,
    unsigned int* __restrict__ flagsA, unsigned int* __restrict__ flagsB)
{
    __shared__ float w1s[128 * 64];   // Wh1 slice [k][c], 32 KB
    __shared__ float w2s[128 * 64];   // Wi2 slice
    __shared__ float w3s[128 * 64];   // Wh2 slice

    const int tid = threadIdx.x;
    const int bk  = blockIdx.x;
    const int rg  = bk >> 7;          // 0..1  row half
    const int kg  = (bk >> 4) & 7;    // 0..7  k-group (128 k)
    const int cg  = bk & 15;          // 0..15 col-group (64 cols)
    const int jj  = bk & 127;         // phase-B role: col-octet jj
    const int k0  = kg * 128;
    const int cs0 = cg * 64;
    const int r0  = rg * 32;

    // ---- stage weight slices (once): 128 k x 64 cols x 3 ----
    for (int idx = tid; idx < 2048; idx += 256) {
        int k = idx >> 4, c4 = (idx & 15) * 4;
        *(f32x4*)&w1s[k * 64 + c4] = *(const f32x4*)(Wh1 + (size_t)(k0 + k) * HID_ + cs0 + c4);
        *(f32x4*)&w2s[k * 64 + c4] = *(const f32x4*)(Wi2 + (size_t)(k0 + k) * HID_ + cs0 + c4);
        *(f32x4*)&w3s[k * 64 + c4] = *(const f32x4*)(Wh2 + (size_t)(k0 + k) * HID_ + cs0 + c4);
    }

    const int row32 = tid >> 3;       // 0..31 (phase A & B row)
    const int c8    = tid & 7;        // 0..7  phase-A col-octet
    const int kq8   = tid & 7;        // 0..7  phase-B kg lane

    const f32x4 b2va = *(const f32x4*)(b2 + jj * 8);
    const f32x4 b2vb = *(const f32x4*)(b2 + jj * 8 + 4);

    float* h1buf[2] = { hb, hb + 65536 };
    float* h2buf[2] = { hb + 131072, hb + 196608 };

    __syncthreads();

    for (int i = 0; i <= S_; ++i) {
        // ---- W1: sparse wait on step-(i-1) phase-B producers (same rg) ----
        // quads: tid 0..3 -> flags [kg*16 .. +16) (h RAW);
        //        tid 4..5 -> flags [cg*8 .. +8)  (p WAR).
        if (i >= 1) {
            const unsigned* fb = flagsB + (size_t)(i - 1) * 256 + rg * 128;
            if (tid < 6) {
                const unsigned* fp = (tid < 4) ? (fb + kg * 16 + tid * 4)
                                               : (fb + cg * 8 + (tid - 4) * 4);
                for (;;) {
                    u32x4 v = ld_coh4u_wait(fp);
                    if (v[0] && v[1] && v[2] && v[3]) break;
                    __builtin_amdgcn_s_sleep(1);
                }
            }
            __syncthreads();
        }

        // ---- phase A: h row (r0+row32), k slice [k0, k0+128) ----
        const float* h1src = h1buf[(i + 1) & 1] + (r0 + row32) * HID_ + k0;
        const float* h2src = h2buf[i & 1]       + (r0 + row32) * HID_ + k0;

        f32x4 a1lo = {0,0,0,0}, a1hi = {0,0,0,0};
        f32x4 a2lo = {0,0,0,0}, a2hi = {0,0,0,0};

        f32x4 A1[4], A2[4], B1[4], B2[4];

        // prologue: batch 0 (k 0..16) into A
#pragma unroll
        for (int r = 0; r < 4; ++r) {
            A1[r] = ld_coh4(h1src + r * 4);
            A2[r] = ld_coh4(h2src + r * 4);
        }

#pragma unroll
        for (int it = 0; it < 8; ++it) {
            if (it < 7) {
                const int kn = (it + 1) * 16;
                if (it & 1) {
#pragma unroll
                    for (int r = 0; r < 4; ++r) {
                        A1[r] = ld_coh4(h1src + kn + r * 4);
                        A2[r] = ld_coh4(h2src + kn + r * 4);
                    }
                } else {
#pragma unroll
                    for (int r = 0; r < 4; ++r) {
                        B1[r] = ld_coh4(h1src + kn + r * 4);
                        B2[r] = ld_coh4(h2src + kn + r * 4);
                    }
                }
            }
            if (it < 7) asm volatile("s_waitcnt vmcnt(8)" ::: "memory");
            else        asm volatile("s_waitcnt vmcnt(0)" ::: "memory");
            __builtin_amdgcn_sched_barrier(0);

            const f32x4* c1 = (it & 1) ? B1 : A1;
            const f32x4* c2 = (it & 1) ? B2 : A2;

#pragma unroll
            for (int q = 0; q < 4; ++q) {
#pragma unroll
                for (int e = 0; e < 4; ++e) {
                    const int kk = it * 16 + q * 4 + e;
                    const float hx = c1[q][e];
                    const float hy = c2[q][e];
                    const float* w1r = &w1s[kk * 64 + c8 * 8];
                    const float* w2r = &w2s[kk * 64 + c8 * 8];
                    const float* w3r = &w3s[kk * 64 + c8 * 8];
                    f32x4 wv1a = *(const f32x4*)(w1r);
                    f32x4 wv1b = *(const f32x4*)(w1r + 4);
                    f32x4 wv2a = *(const f32x4*)(w2r);
                    f32x4 wv2b = *(const f32x4*)(w2r + 4);
                    f32x4 wv3a = *(const f32x4*)(w3r);
                    f32x4 wv3b = *(const f32x4*)(w3r + 4);
                    a1lo += hx * wv1a;  a1hi += hx * wv1b;
                    a2lo += hx * wv2a + hy * wv3a;
                    a2hi += hx * wv2b + hy * wv3b;
                }
            }
        }

        // ---- write partials: ONE full 64B unit per thread ----
        // unit index: (kg*64 + row)*128 + (cg*8 + c8); 16 floats.
        {
            float* pp = pbuf + (((size_t)kg * 64 + r0 + row32) * 128
                                + cg * 8 + c8) * 16;
            st_coh4(pp,      a1lo);
            st_coh4(pp + 4,  a1hi);
            st_coh4(pp + 8,  a2lo);
            st_coh4(pp + 12, a2hi);
        }

        // ---- signal p ready ----
        asm volatile("s_waitcnt vmcnt(0)" ::: "memory");
        __syncthreads();
        if (tid == 0) st_coh1u(flagsA + (size_t)i * 256 + bk, 1u);

        // ---- W2: wait my 8 kg-producers (rg, kg', cg'=jj>>3) ----
        {
            const unsigned* fa = flagsA + (size_t)i * 256 + rg * 128;
            if (tid < 8) {
                while (ld_cohu_wait(fa + tid * 16 + (jj >> 3)) == 0)
                    __builtin_amdgcn_s_sleep(1);
            }
            __syncthreads();
        }

        // ---- phase B: thread (row32, kq8) reads ONE full 64B unit ----
        {
            const float* qp = pbuf + (((size_t)kq8 * 64 + r0 + row32) * 128
                                      + jj) * 16;
            f32x4 s1a = ld_coh4(qp);
            f32x4 s1b = ld_coh4(qp + 4);
            f32x4 s2a = ld_coh4(qp + 8);
            f32x4 s2b = ld_coh4(qp + 12);

            f32x4 xva = {0,0,0,0}, xvb = {0,0,0,0};
            if (i < S_) {   // plain cached (X1 includes b1)
                const float* xp = X1 + ((size_t)i * B_ + r0 + row32) * HID_ + jj * 8;
                xva = *(const f32x4*)(xp);
                xvb = *(const f32x4*)(xp + 4);
            }

            asm volatile("s_waitcnt vmcnt(0)" ::: "memory");
            __builtin_amdgcn_sched_barrier(0);

#pragma unroll
            for (int m = 1; m <= 4; m <<= 1) {
                s1a += shfl_xor4(s1a, m);
                s1b += shfl_xor4(s1b, m);
                s2a += shfl_xor4(s2a, m);
                s2b += shfl_xor4(s2b, m);
            }

            if (kq8 == 0) {
                const int row = r0 + row32;
                if (i < S_) {
                    f32x4 oa, ob;
#pragma unroll
                    for (int e = 0; e < 4; ++e) {
                        oa[e] = tanhf(xva[e] + s1a[e]);
                        ob[e] = tanhf(xvb[e] + s1b[e]);
                    }
                    float* hp = h1buf[i & 1] + row * HID_ + jj * 8;
                    st_coh4(hp, oa); st_coh4(hp + 4, ob);
                }
                if (i >= 1) {
                    f32x4 oa, ob;
#pragma unroll
                    for (int e = 0; e < 4; ++e) {
                        oa[e] = tanhf(s2a[e] + b2va[e]);
                        ob[e] = tanhf(s2b[e] + b2vb[e]);
                    }
                    float* hp = h2buf[(i + 1) & 1] + row * HID_ + jj * 8;
                    st_coh4(hp, oa); st_coh4(hp + 4, ob);
                }
            }
        }

        // ---- signal h ready ----
        if (i < S_) {
            asm volatile("s_waitcnt vmcnt(0)" ::: "memory");
            __syncthreads();
            if (tid == 0) st_coh1u(flagsB + (size_t)i * 256 + bk, 1u);
        }
    }
    // h2(S-1) sits in h2buf[1] (= hb + 196608)
}

// ---------------------------------------------------------------------------
// out[b] = sigmoid(h2_last[b,:] @ Wd + bd)
// ---------------------------------------------------------------------------
__global__ void dense_sigmoid(const float* __restrict__ h2,
                              const float* __restrict__ Wd,
                              const float* __restrict__ bd,
                              float* __restrict__ out)
{
    int b = blockIdx.x, lane = threadIdx.x;
    float s = 0.f;
    for (int j = lane; j < HID_; j += 64) s += h2[b * HID_ + j] * Wd[j];
#pragma unroll
    for (int off = 32; off > 0; off >>= 1) s += __shfl_down(s, off, 64);
    if (lane == 0) out[b] = 1.f / (1.f + expf(-(s + bd[0])));
}

// ---------------------------------------------------------------------------
// ws layout (bytes):
//   hb     @ 0          1,048,576  (4 h buffers fp32)
//   flagsA @ 1,048,576    525,312  (513 steps x 256 u32, [i][bk])
//   flagsB @ 1,573,888    524,288  (512 steps x 256 u32, [i][bk])
//   pbuf   @ 2,098,176  4,194,304  (8 kg x 64 rows x 128 octets x 64B units)
//   X1     @ 6,292,480  134,217,728 (S*B*HID fp32)
// memset zeroes hb+flagsA+flagsB = 2,098,176 B. (pbuf/X1 written before read.)
// ---------------------------------------------------------------------------
extern "C" void kernel_launch(void* const* d_in, const int* in_sizes, int n_in,
                              void* d_out, int out_size, void* d_ws, size_t ws_size,
                              hipStream_t stream)
{
    const int*   x   = (const int*)  d_in[0];
    const float* emb = (const float*)d_in[1];
    const float* Wi1 = (const float*)d_in[2];
    const float* Wh1 = (const float*)d_in[3];
    const float* b1  = (const float*)d_in[4];
    const float* Wi2 = (const float*)d_in[5];
    const float* Wh2 = (const float*)d_in[6];
    const float* b2  = (const float*)d_in[7];
    const float* Wd  = (const float*)d_in[8];
    const float* bd  = (const float*)d_in[9];
    float* out = (float*)d_out;

    char* w = (char*)d_ws;
    float*        hb     = (float*)w;
    unsigned int* flagsA = (unsigned int*)(w + 1048576);
    unsigned int* flagsB = (unsigned int*)(w + 1573888);
    float*        pbuf   = (float*)(w + 2098176);
    float*        X1     = (float*)(w + 6292480);

    hipMemsetAsync(w, 0, 2098176, stream);

    dim3 gA(HID_ / 64, (S_ * B_) / 128);
    embed_gemm<<<gA, dim3(256), 0, stream>>>(x, emb, Wi1, b1, X1);

    const float* X1c = X1;
    void* args[] = { (void*)&X1c, (void*)&Wh1, (void*)&Wi2, (void*)&Wh2,
                     (void*)&b2, (void*)&hb, (void*)&pbuf,
                     (void*)&flagsA, (void*)&flagsB };
    hipLaunchCooperativeKernel((const void*)rnn_scan, dim3(NBLK_), dim3(256),
                               args, 0, stream);

    dense_sigmoid<<<64, 64, 0, stream>>>(hb + 196608, Wd, bd, out);
}

// Round 21
// 11665.445 us; speedup vs baseline: 1.3640x; 1.0450x over previous
//
#include <hip/hip_runtime.h>

#define B_   64
#define S_   512
#define EMB_ 512
#define HID_ 1024
#define NBLK_ 256

typedef float    f32x4 __attribute__((ext_vector_type(4)));
typedef float    f32x2 __attribute__((ext_vector_type(2)));
typedef unsigned u32x4 __attribute__((ext_vector_type(4)));

// Coherent (IC/HBM-path) access: sc0 sc1 bypasses L1+L2. Proven R5..R19.
// RULES: (R9) inline-asm loads need explicit waits. (R12) no runtime-indexed
// ext_vector arrays. (R16) XCC_ID L2-mirror banned. (R18) cached reads +
// acquire fences self-defeat. (R19) pack exchange into 64B units.
// (R20) counted vmcnt ladders in high-pressure compute loops are BANNED —
// only proven wait shapes: issue-all->vmcnt(0)->consume (R8), embedded-wait
// polls (R10), drain-before-signal (R10).
__device__ __forceinline__ f32x4 ld_coh4(const float* p) {
    f32x4 d;
    asm volatile("global_load_dwordx4 %0, %1, off sc0 sc1" : "=v"(d) : "v"(p));
    return d;
}
__device__ __forceinline__ void st_coh4(float* p, f32x4 v) {
    asm volatile("global_store_dwordx4 %0, %1, off sc0 sc1" :: "v"(p), "v"(v) : "memory");
}
__device__ __forceinline__ void st_coh1u(unsigned* p, unsigned v) {
    asm volatile("global_store_dword %0, %1, off sc0 sc1" :: "v"(p), "v"(v) : "memory");
}
__device__ __forceinline__ unsigned ld_cohu_wait(const unsigned* p) {
    unsigned d;
    asm volatile("global_load_dword %0, %1, off sc0 sc1\n\t"
                 "s_waitcnt vmcnt(0)"
                 : "=v"(d) : "v"(p) : "memory");
    return d;
}
__device__ __forceinline__ u32x4 ld_coh4u_wait(const unsigned* p) {
    u32x4 d;
    asm volatile("global_load_dwordx4 %0, %1, off sc0 sc1\n\t"
                 "s_waitcnt vmcnt(0)"
                 : "=v"(d) : "v"(p) : "memory");
    return d;
}

// ---------------------------------------------------------------------------
// Kernel A: X1[t][b][n] = emb[x[b][t]][:] @ Wi1[:,n] + b1[n]  (fp32; chaotic
// recurrence -> no reduced precision anywhere feeding it, R6)
// ---------------------------------------------------------------------------
__global__ __launch_bounds__(256) void embed_gemm(
    const int* __restrict__ x, const float* __restrict__ emb,
    const float* __restrict__ Wi1, const float* __restrict__ b1,
    float* __restrict__ X1)
{
    __shared__ int   tok[128];
    __shared__ float aT[32][132];
    __shared__ float bl[32][68];

    const int tid = threadIdx.x;
    const int m0  = blockIdx.y * 128;
    const int n0  = blockIdx.x * 64;

    if (tid < 128) {
        int m = m0 + tid;
        tok[tid] = x[(m & 63) * S_ + (m >> 6)];
    }
    __syncthreads();

    const int tx = tid & 15;
    const int ty = tid >> 4;

    float acc[8][4];
#pragma unroll
    for (int r = 0; r < 8; ++r)
#pragma unroll
        for (int c = 0; c < 4; ++c) acc[r][c] = 0.f;

    for (int kt = 0; kt < EMB_; kt += 32) {
#pragma unroll
        for (int j = 0; j < 4; ++j) {
            int idx = tid + j * 256;
            int r   = idx >> 3;
            int k4  = (idx & 7) * 4;
            float4 v = *(const float4*)(emb + (size_t)tok[r] * EMB_ + kt + k4);
            aT[k4 + 0][r] = v.x; aT[k4 + 1][r] = v.y;
            aT[k4 + 2][r] = v.z; aT[k4 + 3][r] = v.w;
        }
#pragma unroll
        for (int j = 0; j < 2; ++j) {
            int idx = tid + j * 256;
            int k   = idx >> 4;
            int c4  = (idx & 15) * 4;
            *(float4*)&bl[k][c4] =
                *(const float4*)(Wi1 + (size_t)(kt + k) * HID_ + n0 + c4);
        }
        __syncthreads();

#pragma unroll 4
        for (int k = 0; k < 32; ++k) {
            float4 a0 = *(const float4*)&aT[k][ty * 8];
            float4 a1 = *(const float4*)&aT[k][ty * 8 + 4];
            float4 bv = *(const float4*)&bl[k][tx * 4];
            float ar[8] = {a0.x, a0.y, a0.z, a0.w, a1.x, a1.y, a1.z, a1.w};
            float bc[4] = {bv.x, bv.y, bv.z, bv.w};
#pragma unroll
            for (int r = 0; r < 8; ++r)
#pragma unroll
                for (int c = 0; c < 4; ++c) acc[r][c] += ar[r] * bc[c];
        }
        __syncthreads();
    }

    float4 bias = *(const float4*)(b1 + n0 + tx * 4);
#pragma unroll
    for (int r = 0; r < 8; ++r) {
        int m = m0 + ty * 8 + r;
        float4 o;
        o.x = acc[r][0] + bias.x; o.y = acc[r][1] + bias.y;
        o.z = acc[r][2] + bias.z; o.w = acc[r][3] + bias.w;
        *(float4*)(X1 + (size_t)m * HID_ + n0 + tx * 4) = o;
    }
}

// shfl_xor of a whole f32x4 (per component)
__device__ __forceinline__ f32x4 shfl_xor4(f32x4 v, int m) {
    f32x4 r;
#pragma unroll
    for (int e = 0; e < 4; ++e) r[e] = __shfl_xor(v[e], m, 64);
    return r;
}

// ---------------------------------------------------------------------------
// Kernel B: persistent 3D-split scan (2 x 8 x 16), sparse waits + packed
// 64B pbuf (R19 skeleton). R21: h slice staged into LDS per step (R8's
// proven issue-all->vmcnt(0)->write pattern); compute is pure C — thread
// tile 4 rows x 2 cols, h from LDS (b128), weights from LDS (b64) for 4x
// weight-read reuse. Scratch transpose (verified R20) into 64B pbuf units.
// ---------------------------------------------------------------------------
__global__ __launch_bounds__(256, 1) void rnn_scan(
    const float* __restrict__ X1, const float* __restrict__ Wh1,
    const float* __restrict__ Wi2, const float* __restrict__ Wh2,
    const float* __restrict__ b2, float* __restrict__ hb,
    float* __restrict__ pbuf,
    unsigned int* __restrict__ flagsA, unsigned int* __restrict__ flagsB)
{
    __shared__ float w1s[128 * 64];   // Wh1 slice [k][c], 32 KB (R19 layout)
    __shared__ float w2s[128 * 64];   // Wi2 slice
    __shared__ float w3s[128 * 64];   // Wh2 slice
    __shared__ float h1s[32 * 132];   // h1 slice [row][k], padded, 16.9 KB
    __shared__ float h2s[32 * 132];   // h2 slice
    __shared__ float scr[256 * 20];   // transpose scratch, 20 KB

    const int tid = threadIdx.x;
    const int bk  = blockIdx.x;
    const int rg  = bk >> 7;          // 0..1  row half
    const int kg  = (bk >> 4) & 7;    // 0..7  k-group (128 k)
    const int cg  = bk & 15;          // 0..15 col-group (64 cols)
    const int jj  = bk & 127;         // phase-B role: col-octet jj
    const int k0  = kg * 128;
    const int cs0 = cg * 64;
    const int r0  = rg * 32;

    // ---- stage weight slices (once): verbatim R19 ----
    for (int idx = tid; idx < 2048; idx += 256) {
        int k = idx >> 4, c4 = (idx & 15) * 4;
        *(f32x4*)&w1s[k * 64 + c4] = *(const f32x4*)(Wh1 + (size_t)(k0 + k) * HID_ + cs0 + c4);
        *(f32x4*)&w2s[k * 64 + c4] = *(const f32x4*)(Wi2 + (size_t)(k0 + k) * HID_ + cs0 + c4);
        *(f32x4*)&w3s[k * 64 + c4] = *(const f32x4*)(Wh2 + (size_t)(k0 + k) * HID_ + cs0 + c4);
    }

    const int rq  = tid >> 5;         // 0..7  row quad: local rows 4rq..+4
    const int cq  = tid & 31;         // 0..31 col pair: local cols 2cq, 2cq+1
    const int oct = cq >> 2;          // local col-octet of my cols
    const int pio = (cq & 3) * 2;     // position within octet

    const f32x4 b2va = *(const f32x4*)(b2 + jj * 8);
    const f32x4 b2vb = *(const f32x4*)(b2 + jj * 8 + 4);

    float* h1buf[2] = { hb, hb + 65536 };
    float* h2buf[2] = { hb + 131072, hb + 196608 };

    __syncthreads();

    for (int i = 0; i <= S_; ++i) {
        // ---- W1: sparse wait on step-(i-1) phase-B producers (same rg) ----
        if (i >= 1) {
            const unsigned* fb = flagsB + (size_t)(i - 1) * 256 + rg * 128;
            if (tid < 6) {
                const unsigned* fp = (tid < 4) ? (fb + kg * 16 + tid * 4)
                                               : (fb + cg * 8 + (tid - 4) * 4);
                for (;;) {
                    u32x4 v = ld_coh4u_wait(fp);
                    if (v[0] && v[1] && v[2] && v[3]) break;
                    __builtin_amdgcn_s_sleep(1);
                }
            }
            __syncthreads();
        }

        // ---- stage h slice into LDS (R8 proven pattern) ----
        {
            const float* h1src = h1buf[(i + 1) & 1] + r0 * HID_ + k0;
            const float* h2src = h2buf[i & 1]       + r0 * HID_ + k0;
            f32x4 v1[4], v2[4];
#pragma unroll
            for (int j = 0; j < 4; ++j) {
                int u   = tid + j * 256;       // 0..1023
                int row = u >> 5;              // 0..31
                int kk  = (u & 31) * 4;        // 0..124
                v1[j] = ld_coh4(h1src + row * HID_ + kk);
                v2[j] = ld_coh4(h2src + row * HID_ + kk);
            }
            asm volatile("s_waitcnt vmcnt(0)" ::: "memory");
            __builtin_amdgcn_sched_barrier(0);
#pragma unroll
            for (int j = 0; j < 4; ++j) {
                int u   = tid + j * 256;
                int row = u >> 5;
                int kk  = (u & 31) * 4;
                *(f32x4*)&h1s[row * 132 + kk] = v1[j];
                *(f32x4*)&h2s[row * 132 + kk] = v2[j];
            }
            __syncthreads();
        }

        // ---- phase A compute: pure C, all operands from LDS ----
        const float* h1r = &h1s[(rq * 4) * 132];
        const float* h2r = &h2s[(rq * 4) * 132];
        const float* wp1 = &w1s[cq * 2];
        const float* wp2 = &w2s[cq * 2];
        const float* wp3 = &w3s[cq * 2];

        float a10[2] = {0.f, 0.f}, a11[2] = {0.f, 0.f};
        float a12[2] = {0.f, 0.f}, a13[2] = {0.f, 0.f};
        float a20[2] = {0.f, 0.f}, a21[2] = {0.f, 0.f};
        float a22[2] = {0.f, 0.f}, a23[2] = {0.f, 0.f};

#pragma unroll 4
        for (int kq = 0; kq < 32; ++kq) {
            const int kk = kq * 4;
            f32x4 h1v0 = *(const f32x4*)(h1r + 0 * 132 + kk);
            f32x4 h1v1 = *(const f32x4*)(h1r + 1 * 132 + kk);
            f32x4 h1v2 = *(const f32x4*)(h1r + 2 * 132 + kk);
            f32x4 h1v3 = *(const f32x4*)(h1r + 3 * 132 + kk);
            f32x4 h2v0 = *(const f32x4*)(h2r + 0 * 132 + kk);
            f32x4 h2v1 = *(const f32x4*)(h2r + 1 * 132 + kk);
            f32x4 h2v2 = *(const f32x4*)(h2r + 2 * 132 + kk);
            f32x4 h2v3 = *(const f32x4*)(h2r + 3 * 132 + kk);
#pragma unroll
            for (int j = 0; j < 4; ++j) {
                const int k = kk + j;
                f32x2 wa = *(const f32x2*)(wp1 + k * 64);
                f32x2 wb = *(const f32x2*)(wp2 + k * 64);
                f32x2 wc = *(const f32x2*)(wp3 + k * 64);
                a10[0] += h1v0[j] * wa[0];  a10[1] += h1v0[j] * wa[1];
                a11[0] += h1v1[j] * wa[0];  a11[1] += h1v1[j] * wa[1];
                a12[0] += h1v2[j] * wa[0];  a12[1] += h1v2[j] * wa[1];
                a13[0] += h1v3[j] * wa[0];  a13[1] += h1v3[j] * wa[1];
                a20[0] += h1v0[j] * wb[0] + h2v0[j] * wc[0];
                a20[1] += h1v0[j] * wb[1] + h2v0[j] * wc[1];
                a21[0] += h1v1[j] * wb[0] + h2v1[j] * wc[0];
                a21[1] += h1v1[j] * wb[1] + h2v1[j] * wc[1];
                a22[0] += h1v2[j] * wb[0] + h2v2[j] * wc[0];
                a22[1] += h1v2[j] * wb[1] + h2v2[j] * wc[1];
                a23[0] += h1v3[j] * wb[0] + h2v3[j] * wc[0];
                a23[1] += h1v3[j] * wb[1] + h2v3[j] * wc[1];
            }
        }

        // ---- transpose accums through LDS scratch into 64B pbuf units ----
        // unit (row, oct): su[0..7]=a1 octet cols, su[8..15]=a2 octet cols.
        {
            float* s0 = &scr[((rq * 4 + 0) * 8 + oct) * 20];
            float* s1 = &scr[((rq * 4 + 1) * 8 + oct) * 20];
            float* s2 = &scr[((rq * 4 + 2) * 8 + oct) * 20];
            float* s3 = &scr[((rq * 4 + 3) * 8 + oct) * 20];
            s0[pio] = a10[0]; s0[pio + 1] = a10[1];
            s0[8 + pio] = a20[0]; s0[9 + pio] = a20[1];
            s1[pio] = a11[0]; s1[pio + 1] = a11[1];
            s1[8 + pio] = a21[0]; s1[9 + pio] = a21[1];
            s2[pio] = a12[0]; s2[pio + 1] = a12[1];
            s2[8 + pio] = a22[0]; s2[9 + pio] = a22[1];
            s3[pio] = a13[0]; s3[pio + 1] = a13[1];
            s3[8 + pio] = a23[0]; s3[9 + pio] = a23[1];
        }
        __syncthreads();
        {
            const float* su = &scr[tid * 20];
            f32x4 u0 = *(const f32x4*)(su);
            f32x4 u1 = *(const f32x4*)(su + 4);
            f32x4 u2 = *(const f32x4*)(su + 8);
            f32x4 u3 = *(const f32x4*)(su + 12);
            float* pp = pbuf + (((size_t)kg * 64 + r0 + (tid >> 3)) * 128
                                + cg * 8 + (tid & 7)) * 16;
            st_coh4(pp,      u0);
            st_coh4(pp + 4,  u1);
            st_coh4(pp + 8,  u2);
            st_coh4(pp + 12, u3);
        }

        // ---- signal p ready ----
        asm volatile("s_waitcnt vmcnt(0)" ::: "memory");
        __syncthreads();
        if (tid == 0) st_coh1u(flagsA + (size_t)i * 256 + bk, 1u);

        // ---- W2: wait my 8 kg-producers (rg, kg', cg'=jj>>3) ----
        {
            const unsigned* fa = flagsA + (size_t)i * 256 + rg * 128;
            if (tid < 8) {
                while (ld_cohu_wait(fa + tid * 16 + (jj >> 3)) == 0)
                    __builtin_amdgcn_s_sleep(1);
            }
            __syncthreads();
        }

        // ---- phase B: thread (row32, kq8) reads ONE full 64B unit ----
        {
            const int row32 = tid >> 3;
            const int kq8   = tid & 7;
            const float* qp = pbuf + (((size_t)kq8 * 64 + r0 + row32) * 128
                                      + jj) * 16;
            f32x4 s1a = ld_coh4(qp);
            f32x4 s1b = ld_coh4(qp + 4);
            f32x4 s2a = ld_coh4(qp + 8);
            f32x4 s2b = ld_coh4(qp + 12);

            f32x4 xva = {0,0,0,0}, xvb = {0,0,0,0};
            if (i < S_) {   // plain cached (X1 includes b1)
                const float* xp = X1 + ((size_t)i * B_ + r0 + row32) * HID_ + jj * 8;
                xva = *(const f32x4*)(xp);
                xvb = *(const f32x4*)(xp + 4);
            }

            asm volatile("s_waitcnt vmcnt(0)" ::: "memory");
            __builtin_amdgcn_sched_barrier(0);

#pragma unroll
            for (int m = 1; m <= 4; m <<= 1) {
                s1a += shfl_xor4(s1a, m);
                s1b += shfl_xor4(s1b, m);
                s2a += shfl_xor4(s2a, m);
                s2b += shfl_xor4(s2b, m);
            }

            if (kq8 == 0) {
                const int row = r0 + row32;
                if (i < S_) {
                    f32x4 oa, ob;
#pragma unroll
                    for (int e = 0; e < 4; ++e) {
                        oa[e] = tanhf(xva[e] + s1a[e]);
                        ob[e] = tanhf(xvb[e] + s1b[e]);
                    }
                    float* hp = h1buf[i & 1] + row * HID_ + jj * 8;
                    st_coh4(hp, oa); st_coh4(hp + 4, ob);
                }
                if (i >= 1) {
                    f32x4 oa, ob;
#pragma unroll
                    for (int e = 0; e < 4; ++e) {
                        oa[e] = tanhf(s2a[e] + b2va[e]);
                        ob[e] = tanhf(s2b[e] + b2vb[e]);
                    }
                    float* hp = h2buf[(i + 1) & 1] + row * HID_ + jj * 8;
                    st_coh4(hp, oa); st_coh4(hp + 4, ob);
                }
            }
        }

        // ---- signal h ready ----
        if (i < S_) {
            asm volatile("s_waitcnt vmcnt(0)" ::: "memory");
            __syncthreads();
            if (tid == 0) st_coh1u(flagsB + (size_t)i * 256 + bk, 1u);
        }
    }
    // h2(S-1) sits in h2buf[1] (= hb + 196608)
}

// ---------------------------------------------------------------------------
// out[b] = sigmoid(h2_last[b,:] @ Wd + bd)
// ---------------------------------------------------------------------------
__global__ void dense_sigmoid(const float* __restrict__ h2,
                              const float* __restrict__ Wd,
                              const float* __restrict__ bd,
                              float* __restrict__ out)
{
    int b = blockIdx.x, lane = threadIdx.x;
    float s = 0.f;
    for (int j = lane; j < HID_; j += 64) s += h2[b * HID_ + j] * Wd[j];
#pragma unroll
    for (int off = 32; off > 0; off >>= 1) s += __shfl_down(s, off, 64);
    if (lane == 0) out[b] = 1.f / (1.f + expf(-(s + bd[0])));
}

// ---------------------------------------------------------------------------
// ws layout (bytes) — identical to R19:
//   hb     @ 0          1,048,576  (4 h buffers fp32)
//   flagsA @ 1,048,576    525,312  (513 steps x 256 u32, [i][bk])
//   flagsB @ 1,573,888    524,288  (512 steps x 256 u32, [i][bk])
//   pbuf   @ 2,098,176  4,194,304  (8 kg x 64 rows x 128 octets x 64B units)
//   X1     @ 6,292,480  134,217,728 (S*B*HID fp32)
// memset zeroes hb+flagsA+flagsB = 2,098,176 B. (pbuf/X1 written before read.)
// ---------------------------------------------------------------------------
extern "C" void kernel_launch(void* const* d_in, const int* in_sizes, int n_in,
                              void* d_out, int out_size, void* d_ws, size_t ws_size,
                              hipStream_t stream)
{
    const int*   x   = (const int*)  d_in[0];
    const float* emb = (const float*)d_in[1];
    const float* Wi1 = (const float*)d_in[2];
    const float* Wh1 = (const float*)d_in[3];
    const float* b1  = (const float*)d_in[4];
    const float* Wi2 = (const float*)d_in[5];
    const float* Wh2 = (const float*)d_in[6];
    const float* b2  = (const float*)d_in[7];
    const float* Wd  = (const float*)d_in[8];
    const float* bd  = (const float*)d_in[9];
    float* out = (float*)d_out;

    char* w = (char*)d_ws;
    float*        hb     = (float*)w;
    unsigned int* flagsA = (unsigned int*)(w + 1048576);
    unsigned int* flagsB = (unsigned int*)(w + 1573888);
    float*        pbuf   = (float*)(w + 2098176);
    float*        X1     = (float*)(w + 6292480);

    hipMemsetAsync(w, 0, 2098176, stream);

    dim3 gA(HID_ / 64, (S_ * B_) / 128);
    embed_gemm<<<gA, dim3(256), 0, stream>>>(x, emb, Wi1, b1, X1);

    const float* X1c = X1;
    void* args[] = { (void*)&X1c, (void*)&Wh1, (void*)&Wi2, (void*)&Wh2,
                     (void*)&b2, (void*)&hb, (void*)&pbuf,
                     (void*)&flagsA, (void*)&flagsB };
    hipLaunchCooperativeKernel((const void*)rnn_scan, dim3(NBLK_), dim3(256),
                               args, 0, stream);

    dense_sigmoid<<<64, 64, 0, stream>>>(hb + 196608, Wd, bd, out);
}